// Round 1
// baseline (166.540 us; speedup 1.0000x reference)
//
#include <hip/hip_runtime.h>
#include <hip/hip_bf16.h>

#define D 8196
#define H 4096
#define MLP_HID 32
#define OUT_N 130

__device__ __forceinline__ float sigmoidf_(float v) {
    return 1.0f / (1.0f + expf(-v));
}

__device__ __forceinline__ float dot4(float4 a, float4 b) {
    return a.x * b.x + a.y * b.y + a.z * b.z + a.w * b.w;
}

__device__ __forceinline__ float wave_reduce(float acc) {
    #pragma unroll
    for (int off = 32; off > 0; off >>= 1)
        acc += __shfl_down(acc, off);
    return acc;
}

// One block per hidden unit j. Wave w (0..3) computes gate row w*H + j:
//   gate = W_ih[row,:] . x  +  W_hh[row,:] . h0  +  b_ih[row] + b_hh[row]
// Then thread 0 applies the LSTM cell update and writes h[j].
__global__ __launch_bounds__(256) void lstm_step_kernel(
    const float* __restrict__ x, const float* __restrict__ h0,
    const float* __restrict__ c0,
    const float* __restrict__ W_ih, const float* __restrict__ W_hh,
    const float* __restrict__ b_ih, const float* __restrict__ b_hh,
    float* __restrict__ h_out)
{
    const int j    = blockIdx.x;        // 0..H-1
    const int wave = threadIdx.x >> 6;  // 0..3  (gate: i,f,g,o)
    const int lane = threadIdx.x & 63;
    const int row  = wave * H + j;

    float acc = 0.0f;

    // W_ih[row,:] . x   (D = 8196 -> 2049 float4, 16B-aligned rows)
    {
        const float4* __restrict__ Wr = (const float4*)(W_ih + (size_t)row * D);
        const float4* __restrict__ x4 = (const float4*)x;
        for (int idx = lane; idx < D / 4; idx += 64)
            acc += dot4(Wr[idx], x4[idx]);
    }
    // W_hh[row,:] . h0  (H = 4096 -> 1024 float4, exact multiple of 64)
    {
        const float4* __restrict__ Wr = (const float4*)(W_hh + (size_t)row * H);
        const float4* __restrict__ h4 = (const float4*)h0;
        #pragma unroll 4
        for (int idx = lane; idx < H / 4; idx += 64)
            acc += dot4(Wr[idx], h4[idx]);
    }

    acc = wave_reduce(acc);

    __shared__ float gate[4];
    if (lane == 0)
        gate[wave] = acc + b_ih[row] + b_hh[row];
    __syncthreads();

    if (threadIdx.x == 0) {
        float ig = sigmoidf_(gate[0]);
        float fg = sigmoidf_(gate[1]);
        float gg = tanhf(gate[2]);
        float og = sigmoidf_(gate[3]);
        float c  = fg * c0[j] + ig * gg;
        h_out[j] = og * tanhf(c);
    }
}

// Single block: z = relu(W1 @ h + b1) (32 rows), out = sigmoid(W2 @ z + b2) (130)
__global__ __launch_bounds__(1024) void mlp_head_kernel(
    const float* __restrict__ h,
    const float* __restrict__ W1, const float* __restrict__ b1,
    const float* __restrict__ W2, const float* __restrict__ b2,
    float* __restrict__ out)
{
    __shared__ float z[MLP_HID];
    const int wave = threadIdx.x >> 6;  // 0..15
    const int lane = threadIdx.x & 63;

    for (int r = wave; r < MLP_HID; r += 16) {
        const float4* __restrict__ Wr = (const float4*)(W1 + (size_t)r * H);
        const float4* __restrict__ h4 = (const float4*)h;
        float acc = 0.0f;
        #pragma unroll 4
        for (int idx = lane; idx < H / 4; idx += 64)
            acc += dot4(Wr[idx], h4[idx]);
        acc = wave_reduce(acc);
        if (lane == 0)
            z[r] = fmaxf(acc + b1[r], 0.0f);
    }
    __syncthreads();

    const int t = threadIdx.x;
    if (t < OUT_N) {
        float acc = b2[t];
        #pragma unroll
        for (int k = 0; k < MLP_HID; ++k)
            acc += W2[t * MLP_HID + k] * z[k];
        out[t] = sigmoidf_(acc);
    }
}

extern "C" void kernel_launch(void* const* d_in, const int* in_sizes, int n_in,
                              void* d_out, int out_size, void* d_ws, size_t ws_size,
                              hipStream_t stream) {
    const float* x    = (const float*)d_in[0];
    const float* h0   = (const float*)d_in[1];
    const float* c0   = (const float*)d_in[2];
    const float* W_ih = (const float*)d_in[3];
    const float* W_hh = (const float*)d_in[4];
    const float* b_ih = (const float*)d_in[5];
    const float* b_hh = (const float*)d_in[6];
    const float* W1   = (const float*)d_in[7];
    const float* b1   = (const float*)d_in[8];
    const float* W2   = (const float*)d_in[9];
    const float* b2   = (const float*)d_in[10];
    float* out = (float*)d_out;

    float* h_ws = (float*)d_ws;  // H floats of scratch for the hidden state

    lstm_step_kernel<<<H, 256, 0, stream>>>(x, h0, c0, W_ih, W_hh, b_ih, b_hh, h_ws);
    mlp_head_kernel<<<1, 1024, 0, stream>>>(h_ws, W1, b1, W2, b2, out);
}